// Round 6
// baseline (64.114 us; speedup 1.0000x reference)
//
#include <hip/hip_runtime.h>
#include <math.h>

#define B_SZ 1024
#define D_SZ 2048
#define MARGIN 0.3f

typedef _Float16 f16x8 __attribute__((ext_vector_type(8)));
typedef float f32x16 __attribute__((ext_vector_type(16)));

union FragU { uint4 u; f16x8 v; };
union H4 { _Float16 h[4]; uint2 u; };

#define AS1 __attribute__((address_space(1)))
#define AS3 __attribute__((address_space(3)))

// ws layout (fast path):
// [0, 4MB)            Fh   : fp16, MFMA-fragment-order granules
//   granule g = ((i*128 + kb16)*2 + rg); byte addr g*1024 + lane*16
//   holds F[i*64 + rg*32 + (lane&31)][kb16*16 + (lane>>5)*8 .. +8]
// [4MB, +64KB)        sqpart[16][1024] f32
// then hp / hn / flags (1024 ints each) / done-counter (1 int)

// ---------------- fused prep: fp16 swizzle + sq partials + init ----------------

__global__ __launch_bounds__(256) void prep_kernel(const float* __restrict__ F,
                                                   _Float16* __restrict__ Fh,
                                                   float* __restrict__ sqpart,
                                                   int* __restrict__ hp,
                                                   int* __restrict__ hn,
                                                   int* __restrict__ flags,
                                                   int* __restrict__ counter) {
    __shared__ _Float16 slab[64][136];   // 64 rows x 128 cols, +8 pad
    __shared__ float part[64];

    const int b = blockIdx.x;            // 256 blocks
    const int i = b >> 4;                // 64-row group
    const int kseg = b & 15;             // 128-col segment
    const int t = threadIdx.x;
    const int lane = t & 63;
    const int w = t >> 6;

    const int idx = b * 256 + t;
    if (idx < 1024) {
        hp[idx] = 0;
        hn[idx] = 0x7F800000;
        flags[idx] = 0;
    } else if (idx == 1024) {
        *counter = 0;
    }

#pragma unroll
    for (int q = 0; q < 8; ++q) {
        const int rl = q * 8 + (t >> 5);
        const int c4 = (t & 31) * 4;
        const float4 v = *(const float4*)(F + (size_t)(i * 64 + rl) * D_SZ +
                                          kseg * 128 + c4);
        float s = v.x * v.x + v.y * v.y + v.z * v.z + v.w * v.w;
#pragma unroll
        for (int mask = 1; mask < 32; mask <<= 1) s += __shfl_xor(s, mask);
        if ((t & 31) == 0) part[rl] = s;
        H4 p;
        p.h[0] = (_Float16)v.x; p.h[1] = (_Float16)v.y;
        p.h[2] = (_Float16)v.z; p.h[3] = (_Float16)v.w;
        *(uint2*)&slab[rl][c4] = p.u;
    }
    __syncthreads();

    if (t < 64) sqpart[kseg * 1024 + i * 64 + t] = part[t];

#pragma unroll
    for (int q2 = 0; q2 < 4; ++q2) {
        const int u = w * 4 + q2;
        const int kb = u >> 1;
        const int rg = u & 1;
        const uint4 d = *(const uint4*)&slab[rg * 32 + (lane & 31)]
                                          [kb * 16 + (lane >> 5) * 8];
        const size_t g = (size_t)((i * 128 + kseg * 8 + kb) * 2 + rg);
        *(uint4*)((char*)Fh + g * 1024 + (size_t)lane * 16) = d;
    }
}

// ---------------- dist: DMA-ring fp16 MFMA + fused finalize ----------------
// 512 thr (8 waves, 2/SIMD), K-split 8, 16 sub-steps of K=16,
// ring 3 x 4KB per wave (96KB LDS), counted vmcnt.

__global__ __launch_bounds__(512) void dist_f16_kernel(
    const _Float16* __restrict__ Fh, const int* __restrict__ labels,
    const float* __restrict__ sqpart, int* __restrict__ hp,
    int* __restrict__ hn, int* __restrict__ flags, int* __restrict__ counter,
    float* __restrict__ out) {
    __shared__ __align__(16) char smem[98304];   // ring; reused as combine area
    __shared__ int labR[64], labC[64];
    __shared__ float sqR[64], sqC[64];
    __shared__ float fs[8];
    __shared__ int fv[8], fa[8];
    __shared__ int lastFlag;

    const int t = threadIdx.x;
    const int lane = t & 63;
    const int w = t >> 6;   // K-slice 0..7

    // 4x8 tile chunk per XCD (L2 working set 3MB < 4MB).
    const int xcd = blockIdx.x & 7;
    const int cidx = blockIdx.x >> 3;
    const int bi = (xcd >> 1) * 4 + (cidx >> 3);
    const int bj = (xcd & 1) * 8 + (cidx & 7);
    const int rowBase = bi * 64, colBase = bj * 64;

    if (t < 128) {
        const int e = t & 63;
        const int side = t >> 6;
        const int row = (side ? colBase : rowBase) + e;
        float s = 0.f;
#pragma unroll
        for (int p = 0; p < 16; ++p) s += sqpart[p * 1024 + row];
        if (side) { sqC[e] = s; labC[e] = labels[row]; }
        else      { sqR[e] = s; labR[e] = labels[row]; }
    }
    __syncthreads();
    asm volatile("s_waitcnt vmcnt(0)" ::: "memory");

    const char* __restrict__ FhB = (const char*)Fh;
    char* wbase = smem + w * 12288;            // wave-uniform ring base
    const char* rbase = wbase + lane * 16;     // per-lane read base

    f32x16 acc[2][2];
#pragma unroll
    for (int a = 0; a < 2; ++a)
#pragma unroll
        for (int c = 0; c < 2; ++c)
#pragma unroll
            for (int e = 0; e < 16; ++e) acc[a][c][e] = 0.f;

    auto ISSUE = [&](int s, int b) {
        const int kb16 = w * 16 + s;
        const size_t aOff = ((size_t)((bi * 128 + kb16) * 2)) * 1024 + (size_t)lane * 16;
        const size_t bOff = ((size_t)((bj * 128 + kb16) * 2)) * 1024 + (size_t)lane * 16;
        char* d = wbase + b * 4096;
        __builtin_amdgcn_global_load_lds((const AS1 void*)(FhB + aOff),
                                         (AS3 void*)(d), 16, 0, 0);
        __builtin_amdgcn_global_load_lds((const AS1 void*)(FhB + aOff + 1024),
                                         (AS3 void*)(d + 1024), 16, 0, 0);
        __builtin_amdgcn_global_load_lds((const AS1 void*)(FhB + bOff),
                                         (AS3 void*)(d + 2048), 16, 0, 0);
        __builtin_amdgcn_global_load_lds((const AS1 void*)(FhB + bOff + 1024),
                                         (AS3 void*)(d + 3072), 16, 0, 0);
    };
    auto COMPUTE = [&](int b) {
        const char* rb = rbase + b * 4096;
        FragU a0, a1, v0, v1;
        a0.u = *(const uint4*)(rb);
        a1.u = *(const uint4*)(rb + 1024);
        v0.u = *(const uint4*)(rb + 2048);
        v1.u = *(const uint4*)(rb + 3072);
        acc[0][0] = __builtin_amdgcn_mfma_f32_32x32x16_f16(a0.v, v0.v, acc[0][0], 0, 0, 0);
        acc[0][1] = __builtin_amdgcn_mfma_f32_32x32x16_f16(a0.v, v1.v, acc[0][1], 0, 0, 0);
        acc[1][0] = __builtin_amdgcn_mfma_f32_32x32x16_f16(a1.v, v0.v, acc[1][0], 0, 0, 0);
        acc[1][1] = __builtin_amdgcn_mfma_f32_32x32x16_f16(a1.v, v1.v, acc[1][1], 0, 0, 0);
    };

#define WAITN(n) asm volatile("s_waitcnt vmcnt(" #n ")" ::: "memory"); __builtin_amdgcn_sched_barrier(0)

    ISSUE(0, 0);
    ISSUE(1, 1);
#pragma unroll
    for (int s = 0; s < 16; ++s) {
        if (s + 2 < 16) ISSUE(s + 2, (s + 2) % 3);
        if (s < 14) { WAITN(8); }
        else if (s == 14) { WAITN(4); }
        else { WAITN(0); }
        COMPUTE(s % 3);
    }
#undef WAITN

    __syncthreads();

    // Combine 8 K-partials. Stage 1: waves 4..7 dump, waves 0..3 add partner.
    char* comb = smem;
    if (w >= 4) {
        char* r = comb + (w - 4) * 16384;
#pragma unroll
        for (int fr = 0; fr < 2; ++fr)
#pragma unroll
            for (int fc = 0; fc < 2; ++fc)
#pragma unroll
                for (int g = 0; g < 4; ++g) {
                    float4 v;
                    v.x = acc[fr][fc][g * 4 + 0];
                    v.y = acc[fr][fc][g * 4 + 1];
                    v.z = acc[fr][fc][g * 4 + 2];
                    v.w = acc[fr][fc][g * 4 + 3];
                    *(float4*)(r + (size_t)(((fr * 2 + fc) * 4 + g) * 64 + lane) * 16) = v;
                }
    }
    __syncthreads();
    if (w < 4) {
        const char* r = comb + w * 16384;
#pragma unroll
        for (int fr = 0; fr < 2; ++fr)
#pragma unroll
            for (int fc = 0; fc < 2; ++fc)
#pragma unroll
                for (int g = 0; g < 4; ++g) {
                    float4 v = *(const float4*)(r + (size_t)(((fr * 2 + fc) * 4 + g) * 64 + lane) * 16);
                    acc[fr][fc][g * 4 + 0] += v.x;
                    acc[fr][fc][g * 4 + 1] += v.y;
                    acc[fr][fc][g * 4 + 2] += v.z;
                    acc[fr][fc][g * 4 + 3] += v.w;
                }
    }
    __syncthreads();
    // Stage 2: waves 0..3 exchange; owner o collects slots (o*4+u).
    if (w < 4) {
#pragma unroll
        for (int f = 0; f < 4; ++f) {
            if (f == w) continue;
            char* r = comb + (size_t)(f * 4 + w) * 4096;
            const int fr = f >> 1, fc = f & 1;
#pragma unroll
            for (int g = 0; g < 4; ++g) {
                float4 v;
                v.x = acc[fr][fc][g * 4 + 0];
                v.y = acc[fr][fc][g * 4 + 1];
                v.z = acc[fr][fc][g * 4 + 2];
                v.w = acc[fr][fc][g * 4 + 3];
                *(float4*)(r + (size_t)(g * 64 + lane) * 16) = v;
            }
        }
    }
    __syncthreads();
    if (w < 4) {
        const int fr = w >> 1, fc = w & 1;
        float cS[16];
#pragma unroll
        for (int e = 0; e < 16; ++e) cS[e] = acc[fr][fc][e];
#pragma unroll
        for (int u = 0; u < 4; ++u) {
            if (u == w) continue;
            const char* r = comb + (size_t)(w * 4 + u) * 4096;
#pragma unroll
            for (int g = 0; g < 4; ++g) {
                float4 v = *(const float4*)(r + (size_t)(g * 64 + lane) * 16);
                cS[g * 4 + 0] += v.x;
                cS[g * 4 + 1] += v.y;
                cS[g * 4 + 2] += v.z;
                cS[g * 4 + 3] += v.w;
            }
        }

        const float BIG = 1e38f;
        const int h = lane >> 5;
        const int colL = fc * 32 + (lane & 31);
        const int j = colBase + colL;
        const int lj = labC[colL];
        const float sqj = sqC[colL];
#pragma unroll
        for (int k = 0; k < 16; ++k) {
            const int rowL = fr * 32 + (k & 3) + 8 * (k >> 2) + 4 * h;
            const int i = rowBase + rowL;
            const float d2 = sqR[rowL] + sqj - 2.f * cS[k];
            const float d = sqrtf(fmaxf(d2, 1e-12f));
            const bool eq = (labR[rowL] == lj);
            const bool isPos = eq && (i != j);
            float pv = isPos ? d : -BIG;
            float nv = eq ? BIG : d;
            int pf = (isPos ? 1 : 0) | (eq ? 0 : 2);
#pragma unroll
            for (int mask = 1; mask < 32; mask <<= 1) {
                pv = fmaxf(pv, __shfl_xor(pv, mask));
                nv = fminf(nv, __shfl_xor(nv, mask));
                pf |= __shfl_xor(pf, mask);
            }
            if ((lane & 31) == 0) {
                if (pf & 1) atomicMax(&hp[i], __float_as_int(pv));
                if (pf & 2) atomicMin(&hn[i], __float_as_int(nv));
                if (pf) atomicOr(&flags[i], pf);
            }
        }
    }

    // -------- fused finalize: last block reduces --------
    __syncthreads();
    if (t == 0) {
        __threadfence();
        lastFlag = (atomicAdd(counter, 1) == 255) ? 1 : 0;
    }
    __syncthreads();
    if (lastFlag) {
        __threadfence();
        float s = 0.f;
        int nv = 0, na = 0;
#pragma unroll
        for (int q = 0; q < 2; ++q) {
            const int row = q * 512 + t;
            const float hpv = __int_as_float(hp[row]);
            const float hnv = __int_as_float(hn[row]);
            const bool valid = (flags[row] == 3);
            float pr = fmaxf(hpv - hnv + MARGIN, 0.f);
            if (!valid) pr = 0.f;
            s += pr;
            nv += valid ? 1 : 0;
            na += (valid && pr > 0.f) ? 1 : 0;
        }
#pragma unroll
        for (int m = 1; m < 64; m <<= 1) {
            s += __shfl_xor(s, m);
            nv += __shfl_xor(nv, m);
            na += __shfl_xor(na, m);
        }
        if (lane == 0) { fs[w] = s; fv[w] = nv; fa[w] = na; }
        __syncthreads();
        if (t == 0) {
            float tot = 0.f;
            int NV = 0, NA = 0;
#pragma unroll
            for (int u = 0; u < 8; ++u) {
                tot += fs[u];
                NV += fv[u];
                NA += fa[u];
            }
            out[0] = tot / (float)(NV > 1 ? NV : 1);
            out[1] = (float)NA;
        }
    }
}

// ---------------- fallback path: fp32 vector + final ----------------

#define BM 64
#define BN 64
#define BK 32

__global__ __launch_bounds__(1024) void final_kernel(const int* __restrict__ hp,
                                                     const int* __restrict__ hn,
                                                     const int* __restrict__ flags,
                                                     float* __restrict__ out) {
    __shared__ float ssum[16];
    __shared__ int svalid[16], sact[16];
    const int t = threadIdx.x;
    const float hpv = __int_as_float(hp[t]);
    const float hnv = __int_as_float(hn[t]);
    const int f = flags[t];
    const bool valid = (f == 3);
    float pr = fmaxf(hpv - hnv + MARGIN, 0.f);
    if (!valid) pr = 0.f;
    int act = (valid && pr > 0.f) ? 1 : 0;
    int vld = valid ? 1 : 0;
    float s = pr;
    for (int off = 32; off; off >>= 1) {
        s += __shfl_down(s, off);
        act += __shfl_down(act, off);
        vld += __shfl_down(vld, off);
    }
    if ((t & 63) == 0) {
        ssum[t >> 6] = s;
        svalid[t >> 6] = vld;
        sact[t >> 6] = act;
    }
    __syncthreads();
    if (t == 0) {
        float tot = 0.f;
        int nv = 0, na = 0;
#pragma unroll
        for (int i = 0; i < 16; ++i) {
            tot += ssum[i];
            nv += svalid[i];
            na += sact[i];
        }
        out[0] = tot / (float)(nv > 1 ? nv : 1);
        out[1] = (float)na;
    }
}

__global__ __launch_bounds__(256) void sq_kernel(const float* __restrict__ F,
                                                 float* __restrict__ sq) {
    int row = blockIdx.x;
    const float4* r4 = (const float4*)(F + (size_t)row * D_SZ);
    int t = threadIdx.x;
    float s = 0.f;
#pragma unroll
    for (int q = 0; q < 2; ++q) {
        float4 v = r4[t + q * 256];
        s += v.x * v.x + v.y * v.y + v.z * v.z + v.w * v.w;
    }
    for (int off = 32; off; off >>= 1) s += __shfl_down(s, off);
    __shared__ float wsum[4];
    if ((t & 63) == 0) wsum[t >> 6] = s;
    __syncthreads();
    if (t == 0) sq[row] = wsum[0] + wsum[1] + wsum[2] + wsum[3];
}

__global__ __launch_bounds__(256) void init_kernel(int* __restrict__ hp,
                                                   int* __restrict__ hn,
                                                   int* __restrict__ flags) {
    int i = blockIdx.x * 256 + threadIdx.x;
    hp[i] = 0;
    hn[i] = 0x7F800000;
    flags[i] = 0;
}

__global__ __launch_bounds__(256) void dist_f32_kernel(
    const float* __restrict__ F, const int* __restrict__ labels,
    const float* __restrict__ sq, int* __restrict__ hp, int* __restrict__ hn,
    int* __restrict__ flags) {
    __shared__ float As[BK][BM];
    __shared__ float Bs[BK][BN];
    __shared__ int labR[BM], labC[BN];
    __shared__ float sqR[BM], sqC[BN];

    const int rowBase = blockIdx.y * BM;
    const int colBase = blockIdx.x * BN;
    const int t = threadIdx.x;
    const int tx = t & 15;
    const int ty = t >> 4;

    if (t < 64) {
        labR[t] = labels[rowBase + t];
        sqR[t] = sq[rowBase + t];
    } else if (t < 128) {
        int u = t - 64;
        labC[u] = labels[colBase + u];
        sqC[u] = sq[colBase + u];
    }

    float acc[4][4] = {{0.f}};
    const int m = t & 63;
    const int q = t >> 6;
    const float* aRow = F + (size_t)(rowBase + m) * D_SZ + q * 8;
    const float* bRow = F + (size_t)(colBase + m) * D_SZ + q * 8;

    for (int k0 = 0; k0 < D_SZ; k0 += BK) {
        float4 a0 = *(const float4*)(aRow + k0);
        float4 a1 = *(const float4*)(aRow + k0 + 4);
        float4 b0 = *(const float4*)(bRow + k0);
        float4 b1 = *(const float4*)(bRow + k0 + 4);
        __syncthreads();
        int kb = q * 8;
        As[kb + 0][m] = a0.x; As[kb + 1][m] = a0.y;
        As[kb + 2][m] = a0.z; As[kb + 3][m] = a0.w;
        As[kb + 4][m] = a1.x; As[kb + 5][m] = a1.y;
        As[kb + 6][m] = a1.z; As[kb + 7][m] = a1.w;
        Bs[kb + 0][m] = b0.x; Bs[kb + 1][m] = b0.y;
        Bs[kb + 2][m] = b0.z; Bs[kb + 3][m] = b0.w;
        Bs[kb + 4][m] = b1.x; Bs[kb + 5][m] = b1.y;
        Bs[kb + 6][m] = b1.z; Bs[kb + 7][m] = b1.w;
        __syncthreads();
#pragma unroll
        for (int kk = 0; kk < BK; ++kk) {
            float4 a = *(const float4*)&As[kk][ty * 4];
            float4 b = *(const float4*)&Bs[kk][tx * 4];
            acc[0][0] += a.x * b.x; acc[0][1] += a.x * b.y;
            acc[0][2] += a.x * b.z; acc[0][3] += a.x * b.w;
            acc[1][0] += a.y * b.x; acc[1][1] += a.y * b.y;
            acc[1][2] += a.y * b.z; acc[1][3] += a.y * b.w;
            acc[2][0] += a.z * b.x; acc[2][1] += a.z * b.y;
            acc[2][2] += a.z * b.z; acc[2][3] += a.z * b.w;
            acc[3][0] += a.w * b.x; acc[3][1] += a.w * b.y;
            acc[3][2] += a.w * b.z; acc[3][3] += a.w * b.w;
        }
    }

    float mp[4], mn[4];
    int pf[4];
#pragma unroll
    for (int rr = 0; rr < 4; ++rr) {
        const int i = rowBase + ty * 4 + rr;
        const int li = labR[ty * 4 + rr];
        const float si = sqR[ty * 4 + rr];
        mp[rr] = -3.4e38f;
        mn[rr] = 3.4e38f;
        pf[rr] = 0;
#pragma unroll
        for (int c = 0; c < 4; ++c) {
            const int j = colBase + tx * 4 + c;
            const float d2 = si + sqC[tx * 4 + c] - 2.f * acc[rr][c];
            const float dist = sqrtf(fmaxf(d2, 1e-12f));
            const bool eq = (li == labC[tx * 4 + c]);
            if (eq && (i != j)) {
                mp[rr] = fmaxf(mp[rr], dist);
                pf[rr] |= 1;
            }
            if (!eq) {
                mn[rr] = fminf(mn[rr], dist);
                pf[rr] |= 2;
            }
        }
    }
#pragma unroll
    for (int mask = 1; mask < 16; mask <<= 1)
#pragma unroll
        for (int rr = 0; rr < 4; ++rr) {
            mp[rr] = fmaxf(mp[rr], __shfl_xor(mp[rr], mask));
            mn[rr] = fminf(mn[rr], __shfl_xor(mn[rr], mask));
            pf[rr] |= __shfl_xor(pf[rr], mask);
        }
    if (tx == 0) {
#pragma unroll
        for (int rr = 0; rr < 4; ++rr) {
            const int i = rowBase + ty * 4 + rr;
            if (pf[rr] & 1) atomicMax(&hp[i], __float_as_int(mp[rr]));
            if (pf[rr] & 2) atomicMin(&hn[i], __float_as_int(mn[rr]));
            if (pf[rr]) atomicOr(&flags[i], pf[rr]);
        }
    }
}

// ---------------- launch ----------------

extern "C" void kernel_launch(void* const* d_in, const int* in_sizes, int n_in,
                              void* d_out, int out_size, void* d_ws, size_t ws_size,
                              hipStream_t stream) {
    const float* F = (const float*)d_in[0];
    const int* labels = (const int*)d_in[1];
    float* out = (float*)d_out;
    char* ws = (char*)d_ws;

    const size_t FH = (size_t)B_SZ * D_SZ * 2;         // 4MB fp16 swizzled
    const size_t SQP = 16 * 1024 * sizeof(float);      // 64KB
    const size_t need = FH + SQP + 12 * 1024 + 64;

    if (ws_size >= need) {
        _Float16* Fh = (_Float16*)ws;
        float* sqpart = (float*)(ws + FH);
        char* tail = ws + FH + SQP;
        int* hp = (int*)tail;
        int* hn = (int*)(tail + 4096);
        int* flags = (int*)(tail + 8192);
        int* counter = (int*)(tail + 12288);

        prep_kernel<<<256, 256, 0, stream>>>(F, Fh, sqpart, hp, hn, flags, counter);
        dist_f16_kernel<<<256, 512, 0, stream>>>(Fh, labels, sqpart, hp, hn, flags,
                                                 counter, out);
    } else {
        float* sq = (float*)ws;
        int* hp = (int*)(ws + 4096);
        int* hn = (int*)(ws + 8192);
        int* flags = (int*)(ws + 12288);

        sq_kernel<<<B_SZ, 256, 0, stream>>>(F, sq);
        init_kernel<<<B_SZ / 256, 256, 0, stream>>>(hp, hn, flags);
        dim3 grid(B_SZ / BN, B_SZ / BM);
        dist_f32_kernel<<<grid, 256, 0, stream>>>(F, labels, sq, hp, hn, flags);
        final_kernel<<<1, 1024, 0, stream>>>(hp, hn, flags, out);
    }
}

// Round 7
// 31.915 us; speedup vs baseline: 2.0089x; 2.0089x over previous
//
#include <hip/hip_runtime.h>
#include <math.h>

#define B_SZ 1024
#define D_SZ 2048
#define MARGIN 0.3f

typedef _Float16 f16x8 __attribute__((ext_vector_type(8)));
typedef float f32x16 __attribute__((ext_vector_type(16)));

union FragU { uint4 u; f16x8 v; };
union H4 { _Float16 h[4]; uint2 u; };

#define AS1 __attribute__((address_space(1)))
#define AS3 __attribute__((address_space(3)))

// ws layout (fast path):
// [0, 4MB)       Fh : fp16, MFMA-fragment-order granules
//   granule g = ((i*128 + kb16)*2 + rg); byte addr g*1024 + lane*16
//   holds F[i*64 + rg*32 + (lane&31)][kb16*16 + (lane>>5)*8 .. +8]
// [4MB, +64KB)   sqpart[16][1024] f32
// then hp / hn / flags (1024 ints each)

// ---------------- fused prep: fp16 swizzle + sq partials + init ----------------

__global__ __launch_bounds__(256) void prep_kernel(const float* __restrict__ F,
                                                   _Float16* __restrict__ Fh,
                                                   float* __restrict__ sqpart,
                                                   int* __restrict__ hp,
                                                   int* __restrict__ hn,
                                                   int* __restrict__ flags) {
    __shared__ _Float16 slab[64][136];   // 64 rows x 128 cols, +8 pad
    __shared__ float part[64];

    const int b = blockIdx.x;            // 256 blocks
    const int i = b >> 4;                // 64-row group
    const int kseg = b & 15;             // 128-col segment
    const int t = threadIdx.x;
    const int lane = t & 63;
    const int w = t >> 6;

    const int idx = b * 256 + t;
    if (idx < 1024) {
        hp[idx] = 0;                     // 0.0f bits; real dists are > 0
        hn[idx] = 0x7F800000;            // +inf
        flags[idx] = 0;
    }

#pragma unroll
    for (int q = 0; q < 8; ++q) {
        const int rl = q * 8 + (t >> 5);
        const int c4 = (t & 31) * 4;
        const float4 v = *(const float4*)(F + (size_t)(i * 64 + rl) * D_SZ +
                                          kseg * 128 + c4);
        float s = v.x * v.x + v.y * v.y + v.z * v.z + v.w * v.w;
#pragma unroll
        for (int mask = 1; mask < 32; mask <<= 1) s += __shfl_xor(s, mask);
        if ((t & 31) == 0) part[rl] = s;
        H4 p;
        p.h[0] = (_Float16)v.x; p.h[1] = (_Float16)v.y;
        p.h[2] = (_Float16)v.z; p.h[3] = (_Float16)v.w;
        *(uint2*)&slab[rl][c4] = p.u;
    }
    __syncthreads();

    if (t < 64) sqpart[kseg * 1024 + i * 64 + t] = part[t];

#pragma unroll
    for (int q2 = 0; q2 < 4; ++q2) {
        const int u = w * 4 + q2;
        const int kb = u >> 1;
        const int rg = u & 1;
        const uint4 d = *(const uint4*)&slab[rg * 32 + (lane & 31)]
                                          [kb * 16 + (lane >> 5) * 8];
        const size_t g = (size_t)((i * 128 + kseg * 8 + kb) * 2 + rg);
        *(uint4*)((char*)Fh + g * 1024 + (size_t)lane * 16) = d;
    }
}

// ---------------- dist: DMA-ring fp16 MFMA (bench-R3 structure, 256 thr) -----
// 4 waves, K-split 4 (K=512/wave), 16 sub-steps of K=32,
// ring 3 x 8KB per wave (96KB LDS), counted vmcnt(16/8/0).

#define WAVE_STAGE (3 * 8192)

__global__ __launch_bounds__(256) void dist_f16_kernel(
    const _Float16* __restrict__ Fh, const int* __restrict__ labels,
    const float* __restrict__ sqpart, int* __restrict__ hp,
    int* __restrict__ hn, int* __restrict__ flags) {
    __shared__ __align__(16) char stage[4 * WAVE_STAGE];   // 96KB; reused for combine
    __shared__ int labR[64], labC[64];
    __shared__ float sqR[64], sqC[64];

    const int t = threadIdx.x;
    const int lane = t & 63;
    const int w = t >> 6;   // wave id = K-quarter

    // XCD-friendly bijective swizzle (measured-good in bench R3).
    const int tileId = (blockIdx.x & 7) * 32 + (blockIdx.x >> 3);
    const int bi = tileId >> 4;
    const int bj = tileId & 15;
    const int rowBase = bi * 64, colBase = bj * 64;

    if (t < 128) {
        const int e = t & 63;
        const int side = t >> 6;
        const int row = (side ? colBase : rowBase) + e;
        float s = 0.f;
#pragma unroll
        for (int p = 0; p < 16; ++p) s += sqpart[p * 1024 + row];
        if (side) { sqC[e] = s; labC[e] = labels[row]; }
        else      { sqR[e] = s; labR[e] = labels[row]; }
    }
    __syncthreads();
    asm volatile("s_waitcnt vmcnt(0)" ::: "memory");   // clean vmcnt before counted loop

    const char* __restrict__ FhB = (const char*)Fh;
    char* wbase = stage + w * WAVE_STAGE;          // wave-uniform
    const char* rbase = wbase + lane * 16;         // per-lane read base

    f32x16 acc[2][2];
#pragma unroll
    for (int a = 0; a < 2; ++a)
#pragma unroll
        for (int c = 0; c < 2; ++c)
#pragma unroll
            for (int e = 0; e < 16; ++e) acc[a][c][e] = 0.f;

    // Issue one K=32 sub-step (8 x global_load_lds of 1KB, all contiguous).
    auto ISSUE = [&](int s, int b) {
        const int kb16 = w * 32 + s * 2;
        const size_t aOff = (size_t)((bi * 128 + kb16) * 2) * 1024 + (size_t)lane * 16;
        const size_t bOff = (size_t)((bj * 128 + kb16) * 2) * 1024 + (size_t)lane * 16;
        char* dA = wbase + b * 8192;
#pragma unroll
        for (int c = 0; c < 4; ++c)
            __builtin_amdgcn_global_load_lds(
                (const AS1 void*)(FhB + aOff + c * 1024),
                (AS3 void*)(dA + c * 1024), 16, 0, 0);
#pragma unroll
        for (int c = 0; c < 4; ++c)
            __builtin_amdgcn_global_load_lds(
                (const AS1 void*)(FhB + bOff + c * 1024),
                (AS3 void*)(dA + 4096 + c * 1024), 16, 0, 0);
    };
    // Consume one staged K=32 sub-step: 8 ds_read_b128 + 8 MFMA.
    auto COMPUTE = [&](int b) {
        const char* rb = rbase + b * 8192;
#pragma unroll
        for (int kl = 0; kl < 2; ++kl) {
            FragU a0, a1, v0, v1;
            a0.u = *(const uint4*)(rb + (kl * 2 + 0) * 1024);
            a1.u = *(const uint4*)(rb + (kl * 2 + 1) * 1024);
            v0.u = *(const uint4*)(rb + 4096 + (kl * 2 + 0) * 1024);
            v1.u = *(const uint4*)(rb + 4096 + (kl * 2 + 1) * 1024);
            acc[0][0] = __builtin_amdgcn_mfma_f32_32x32x16_f16(a0.v, v0.v, acc[0][0], 0, 0, 0);
            acc[0][1] = __builtin_amdgcn_mfma_f32_32x32x16_f16(a0.v, v1.v, acc[0][1], 0, 0, 0);
            acc[1][0] = __builtin_amdgcn_mfma_f32_32x32x16_f16(a1.v, v0.v, acc[1][0], 0, 0, 0);
            acc[1][1] = __builtin_amdgcn_mfma_f32_32x32x16_f16(a1.v, v1.v, acc[1][1], 0, 0, 0);
        }
    };

#define WAIT16 asm volatile("s_waitcnt vmcnt(16)" ::: "memory"); __builtin_amdgcn_sched_barrier(0)
#define WAIT8  asm volatile("s_waitcnt vmcnt(8)"  ::: "memory"); __builtin_amdgcn_sched_barrier(0)
#define WAIT0  asm volatile("s_waitcnt vmcnt(0)"  ::: "memory"); __builtin_amdgcn_sched_barrier(0)

    ISSUE(0, 0);
    ISSUE(1, 1);
    for (int s3 = 0; s3 < 12; s3 += 3) {   // s = 0..11
        ISSUE(s3 + 2, 2); WAIT16; COMPUTE(0);
        ISSUE(s3 + 3, 0); WAIT16; COMPUTE(1);
        ISSUE(s3 + 4, 1); WAIT16; COMPUTE(2);
    }
    ISSUE(14, 2); WAIT16; COMPUTE(0);      // s = 12
    ISSUE(15, 0); WAIT16; COMPUTE(1);      // s = 13
    WAIT8;  COMPUTE(2);                    // s = 14
    WAIT0;  COMPUTE(0);                    // s = 15

#undef WAIT16
#undef WAIT8
#undef WAIT0

    __syncthreads();

    // Combine the 4 K-partials through LDS (reuse staging area, 64KB).
    char* cb = stage;
#pragma unroll
    for (int fr = 0; fr < 2; ++fr)
#pragma unroll
        for (int fc = 0; fc < 2; ++fc)
#pragma unroll
            for (int g = 0; g < 4; ++g) {
                float4 v;
                v.x = acc[fr][fc][g * 4 + 0];
                v.y = acc[fr][fc][g * 4 + 1];
                v.z = acc[fr][fc][g * 4 + 2];
                v.w = acc[fr][fc][g * 4 + 3];
                *(float4*)(cb + ((size_t)((w * 16 + (fr * 2 + fc) * 4 + g) * 64 + lane)) * 16) = v;
            }
    __syncthreads();

    // Wave w owns frag (fr,fc) = (w>>1, w&1): sum 4 partials, then epilogue.
    const int fr = w >> 1, fc = w & 1;
    float cS[16];
#pragma unroll
    for (int e = 0; e < 16; ++e) cS[e] = 0.f;
#pragma unroll
    for (int wp = 0; wp < 4; ++wp)
#pragma unroll
        for (int g = 0; g < 4; ++g) {
            float4 v = *(const float4*)(cb + ((size_t)((wp * 16 + w * 4 + g) * 64 + lane)) * 16);
            cS[g * 4 + 0] += v.x;
            cS[g * 4 + 1] += v.y;
            cS[g * 4 + 2] += v.z;
            cS[g * 4 + 3] += v.w;
        }

    const float BIG = 1e38f;
    const int h = lane >> 5;
    const int colL = fc * 32 + (lane & 31);
    const int j = colBase + colL;
    const int lj = labC[colL];
    const float sqj = sqC[colL];
#pragma unroll
    for (int k = 0; k < 16; ++k) {
        const int rowL = fr * 32 + (k & 3) + 8 * (k >> 2) + 4 * h;
        const int i = rowBase + rowL;
        const float d2 = sqR[rowL] + sqj - 2.f * cS[k];
        const float d = sqrtf(fmaxf(d2, 1e-12f));
        const bool eq = (labR[rowL] == lj);
        const bool isPos = eq && (i != j);
        float pv = isPos ? d : -BIG;
        float nv = eq ? BIG : d;
        int pf = (isPos ? 1 : 0) | (eq ? 0 : 2);
#pragma unroll
        for (int mask = 1; mask < 32; mask <<= 1) {
            pv = fmaxf(pv, __shfl_xor(pv, mask));
            nv = fminf(nv, __shfl_xor(nv, mask));
            pf |= __shfl_xor(pf, mask);
        }
        if ((lane & 31) == 0) {
            if (pf & 1) atomicMax(&hp[i], __float_as_int(pv));
            if (pf & 2) atomicMin(&hn[i], __float_as_int(nv));
            if (pf) atomicOr(&flags[i], pf);
        }
    }
}

// ---------------- final ----------------

__global__ __launch_bounds__(1024) void final_kernel(const int* __restrict__ hp,
                                                     const int* __restrict__ hn,
                                                     const int* __restrict__ flags,
                                                     float* __restrict__ out) {
    __shared__ float ssum[16];
    __shared__ int svalid[16], sact[16];
    const int t = threadIdx.x;
    const float hpv = __int_as_float(hp[t]);
    const float hnv = __int_as_float(hn[t]);
    const int f = flags[t];
    const bool valid = (f == 3);
    float pr = fmaxf(hpv - hnv + MARGIN, 0.f);
    if (!valid) pr = 0.f;
    int act = (valid && pr > 0.f) ? 1 : 0;
    int vld = valid ? 1 : 0;
    float s = pr;
    for (int off = 32; off; off >>= 1) {
        s += __shfl_down(s, off);
        act += __shfl_down(act, off);
        vld += __shfl_down(vld, off);
    }
    if ((t & 63) == 0) {
        ssum[t >> 6] = s;
        svalid[t >> 6] = vld;
        sact[t >> 6] = act;
    }
    __syncthreads();
    if (t == 0) {
        float tot = 0.f;
        int nv = 0, na = 0;
#pragma unroll
        for (int i = 0; i < 16; ++i) {
            tot += ssum[i];
            nv += svalid[i];
            na += sact[i];
        }
        out[0] = tot / (float)(nv > 1 ? nv : 1);
        out[1] = (float)na;
    }
}

// ---------------- fallback path: fp32 vector ----------------

#define BM 64
#define BN 64
#define BK 32

__global__ __launch_bounds__(256) void sq_kernel(const float* __restrict__ F,
                                                 float* __restrict__ sq) {
    int row = blockIdx.x;
    const float4* r4 = (const float4*)(F + (size_t)row * D_SZ);
    int t = threadIdx.x;
    float s = 0.f;
#pragma unroll
    for (int q = 0; q < 2; ++q) {
        float4 v = r4[t + q * 256];
        s += v.x * v.x + v.y * v.y + v.z * v.z + v.w * v.w;
    }
    for (int off = 32; off; off >>= 1) s += __shfl_down(s, off);
    __shared__ float wsum[4];
    if ((t & 63) == 0) wsum[t >> 6] = s;
    __syncthreads();
    if (t == 0) sq[row] = wsum[0] + wsum[1] + wsum[2] + wsum[3];
}

__global__ __launch_bounds__(256) void init_kernel(int* __restrict__ hp,
                                                   int* __restrict__ hn,
                                                   int* __restrict__ flags) {
    int i = blockIdx.x * 256 + threadIdx.x;
    hp[i] = 0;
    hn[i] = 0x7F800000;
    flags[i] = 0;
}

__global__ __launch_bounds__(256) void dist_f32_kernel(
    const float* __restrict__ F, const int* __restrict__ labels,
    const float* __restrict__ sq, int* __restrict__ hp, int* __restrict__ hn,
    int* __restrict__ flags) {
    __shared__ float As[BK][BM];
    __shared__ float Bs[BK][BN];
    __shared__ int labR[BM], labC[BN];
    __shared__ float sqR[BM], sqC[BN];

    const int rowBase = blockIdx.y * BM;
    const int colBase = blockIdx.x * BN;
    const int t = threadIdx.x;
    const int tx = t & 15;
    const int ty = t >> 4;

    if (t < 64) {
        labR[t] = labels[rowBase + t];
        sqR[t] = sq[rowBase + t];
    } else if (t < 128) {
        int u = t - 64;
        labC[u] = labels[colBase + u];
        sqC[u] = sq[colBase + u];
    }

    float acc[4][4] = {{0.f}};
    const int m = t & 63;
    const int q = t >> 6;
    const float* aRow = F + (size_t)(rowBase + m) * D_SZ + q * 8;
    const float* bRow = F + (size_t)(colBase + m) * D_SZ + q * 8;

    for (int k0 = 0; k0 < D_SZ; k0 += BK) {
        float4 a0 = *(const float4*)(aRow + k0);
        float4 a1 = *(const float4*)(aRow + k0 + 4);
        float4 b0 = *(const float4*)(bRow + k0);
        float4 b1 = *(const float4*)(bRow + k0 + 4);
        __syncthreads();
        int kb = q * 8;
        As[kb + 0][m] = a0.x; As[kb + 1][m] = a0.y;
        As[kb + 2][m] = a0.z; As[kb + 3][m] = a0.w;
        As[kb + 4][m] = a1.x; As[kb + 5][m] = a1.y;
        As[kb + 6][m] = a1.z; As[kb + 7][m] = a1.w;
        Bs[kb + 0][m] = b0.x; Bs[kb + 1][m] = b0.y;
        Bs[kb + 2][m] = b0.z; Bs[kb + 3][m] = b0.w;
        Bs[kb + 4][m] = b1.x; Bs[kb + 5][m] = b1.y;
        Bs[kb + 6][m] = b1.z; Bs[kb + 7][m] = b1.w;
        __syncthreads();
#pragma unroll
        for (int kk = 0; kk < BK; ++kk) {
            float4 a = *(const float4*)&As[kk][ty * 4];
            float4 b = *(const float4*)&Bs[kk][tx * 4];
            acc[0][0] += a.x * b.x; acc[0][1] += a.x * b.y;
            acc[0][2] += a.x * b.z; acc[0][3] += a.x * b.w;
            acc[1][0] += a.y * b.x; acc[1][1] += a.y * b.y;
            acc[1][2] += a.y * b.z; acc[1][3] += a.y * b.w;
            acc[2][0] += a.z * b.x; acc[2][1] += a.z * b.y;
            acc[2][2] += a.z * b.z; acc[2][3] += a.z * b.w;
            acc[3][0] += a.w * b.x; acc[3][1] += a.w * b.y;
            acc[3][2] += a.w * b.z; acc[3][3] += a.w * b.w;
        }
    }

    float mp[4], mn[4];
    int pf[4];
#pragma unroll
    for (int rr = 0; rr < 4; ++rr) {
        const int i = rowBase + ty * 4 + rr;
        const int li = labR[ty * 4 + rr];
        const float si = sqR[ty * 4 + rr];
        mp[rr] = -3.4e38f;
        mn[rr] = 3.4e38f;
        pf[rr] = 0;
#pragma unroll
        for (int c = 0; c < 4; ++c) {
            const int j = colBase + tx * 4 + c;
            const float d2 = si + sqC[tx * 4 + c] - 2.f * acc[rr][c];
            const float dist = sqrtf(fmaxf(d2, 1e-12f));
            const bool eq = (li == labC[tx * 4 + c]);
            if (eq && (i != j)) {
                mp[rr] = fmaxf(mp[rr], dist);
                pf[rr] |= 1;
            }
            if (!eq) {
                mn[rr] = fminf(mn[rr], dist);
                pf[rr] |= 2;
            }
        }
    }
#pragma unroll
    for (int mask = 1; mask < 16; mask <<= 1)
#pragma unroll
        for (int rr = 0; rr < 4; ++rr) {
            mp[rr] = fmaxf(mp[rr], __shfl_xor(mp[rr], mask));
            mn[rr] = fminf(mn[rr], __shfl_xor(mn[rr], mask));
            pf[rr] |= __shfl_xor(pf[rr], mask);
        }
    if (tx == 0) {
#pragma unroll
        for (int rr = 0; rr < 4; ++rr) {
            const int i = rowBase + ty * 4 + rr;
            if (pf[rr] & 1) atomicMax(&hp[i], __float_as_int(mp[rr]));
            if (pf[rr] & 2) atomicMin(&hn[i], __float_as_int(mn[rr]));
            if (pf[rr]) atomicOr(&flags[i], pf[rr]);
        }
    }
}

// ---------------- launch ----------------

extern "C" void kernel_launch(void* const* d_in, const int* in_sizes, int n_in,
                              void* d_out, int out_size, void* d_ws, size_t ws_size,
                              hipStream_t stream) {
    const float* F = (const float*)d_in[0];
    const int* labels = (const int*)d_in[1];
    float* out = (float*)d_out;
    char* ws = (char*)d_ws;

    const size_t FH = (size_t)B_SZ * D_SZ * 2;         // 4MB fp16 swizzled
    const size_t SQP = 16 * 1024 * sizeof(float);      // 64KB
    const size_t need = FH + SQP + 12 * 1024;

    if (ws_size >= need) {
        _Float16* Fh = (_Float16*)ws;
        float* sqpart = (float*)(ws + FH);
        char* tail = ws + FH + SQP;
        int* hp = (int*)tail;
        int* hn = (int*)(tail + 4096);
        int* flags = (int*)(tail + 8192);

        prep_kernel<<<256, 256, 0, stream>>>(F, Fh, sqpart, hp, hn, flags);
        dist_f16_kernel<<<256, 256, 0, stream>>>(Fh, labels, sqpart, hp, hn, flags);
        final_kernel<<<1, 1024, 0, stream>>>(hp, hn, flags, out);
    } else {
        float* sq = (float*)ws;
        int* hp = (int*)(ws + 4096);
        int* hn = (int*)(ws + 8192);
        int* flags = (int*)(ws + 12288);

        sq_kernel<<<B_SZ, 256, 0, stream>>>(F, sq);
        init_kernel<<<B_SZ / 256, 256, 0, stream>>>(hp, hn, flags);
        dim3 grid(B_SZ / BN, B_SZ / BM);
        dist_f32_kernel<<<grid, 256, 0, stream>>>(F, labels, sq, hp, hn, flags);
        final_kernel<<<1, 1024, 0, stream>>>(hp, hn, flags, out);
    }
}